// Round 7
// baseline (353.966 us; speedup 1.0000x reference)
//
#include <hip/hip_runtime.h>
#include <math.h>

// MLA decode attention (fp32), flash-decoding split over sequence chunks.
// B=64, H=16, latent D=576, V=512, MAX_LEN=4096.
//
// R6: barrier-free wave-per-block structure.
//  - Evidence R3/R4/R5: every VGPR-costing "optimization" regressed vs R2
//    (224us); R2's residual vs the ~40us issue floor is per-tile barrier
//    convoys (whole-block vmcnt drains) + coarse (45us-block) tail imbalance,
//    not LDS/stage throughput.
//  - Block = ONE wave (64 threads) owning (batch, chunk, 4 heads). K/V rows
//    read DIRECTLY from global: the 16 lanes of a dd-group cover one 256B
//    segment, 4 head-groups issue identical addresses -> HW broadcast
//    coalescing, same transaction count as the LDS path. V retained in
//    registers for PV. ZERO __syncthreads / LDS / global_load_lds.
//  - The 4 sibling blocks of one (b,c) re-read the same rows: block IDs are
//    constructed = p%8 (mod 8) apart so they land on the SAME XCD (typical
//    round-robin dispatch) and re-reads hit the 4MB XCD-L2. Wrong
//    assumption costs L3 hits, not correctness.
//  - ~116 VGPR -> 4 waves/SIMD = 16 independent waves/CU; 8192 small blocks
//    give fine-grained load balance over random context_lens.
//  - Keeps: log2-domain softmax w/ scale folded into Q, defer-max (THR=8),
//    per-head (m,l) uniform in 16-lane groups, flash-decoding reduce kernel.

namespace {
constexpr int NB = 64;
constexpr int NH = 16;
constexpr int MAXLEN = 4096;
constexpr int D = 576;
constexpr int DV = 512;
constexpr float SCALE_LOG2E = 0.041666666666666664f * 1.4426950408889634f;
constexpr float NEGINF = -1e30f;
constexpr float THR2 = 8.0f;  // defer-max threshold (log2 domain)
}

__global__ __launch_bounds__(64, 4)
void mla_wave(const float* __restrict__ qg,
              const float* __restrict__ kvnew,
              const float* __restrict__ cache,
              const int* __restrict__ lens,
              float* __restrict__ ws_o,
              float* __restrict__ ws_ml,
              int nchunk, int chunk)
{
    // id = xcd + 8*(hg + 4*phi): the 4 head-group siblings of a (b,c) pair
    // share id%8 -> same XCD under round-robin dispatch.
    const int id = (int)blockIdx.x;
    const int xcd = id & 7;
    const int t = id >> 3;
    const int hg = t & 3;
    const int p = ((t >> 2) << 3) | xcd;      // (b,c) pair index
    const int b = p / nchunk;
    const int c = p - b * nchunk;

    const int total = lens[b] + 1;
    const int start = c * chunk;
    if (start >= total) return;
    const int end = min(start + chunk, total);
    const int newpos = total - 1;

    const int lane = (int)threadIdx.x;
    const int hl = lane >> 4;            // head within group of 4
    const int dd = lane & 15;            // d-slice (16B granule)
    const int head = hg * 4 + hl;

    // Q into registers, softmax scale pre-folded (log2 domain)
    float4 q[9];
    {
        const float* qp = qg + ((size_t)b * NH + head) * D + dd * 4;
        #pragma unroll
        for (int j = 0; j < 9; ++j) {
            float4 v = *(const float4*)(qp + j * 64);
            v.x *= SCALE_LOG2E; v.y *= SCALE_LOG2E;
            v.z *= SCALE_LOG2E; v.w *= SCALE_LOG2E;
            q[j] = v;
        }
    }

    float4 acc[8];
    #pragma unroll
    for (int j = 0; j < 8; ++j) acc[j] = make_float4(0.f, 0.f, 0.f, 0.f);
    float m2 = NEGINF, l = 0.f;

    const float* base = cache + (size_t)b * MAXLEN * D + dd * 4;
    const float* vnew = kvnew + (size_t)b * D + dd * 4;

    for (int row = start; row < end; ++row) {
        const float* src = (row == newpos) ? vnew
                                           : (base + (size_t)row * D);
        float4 x[9];
        #pragma unroll
        for (int j = 0; j < 9; ++j)
            x[j] = *(const float4*)(src + j * 64);

        // dot: two independent partial chains
        float s0 = 0.f, s1 = 0.f;
        #pragma unroll
        for (int j = 0; j < 9; ++j) {
            if (j & 1) {
                s1 = fmaf(x[j].x, q[j].x, s1);
                s1 = fmaf(x[j].y, q[j].y, s1);
                s1 = fmaf(x[j].z, q[j].z, s1);
                s1 = fmaf(x[j].w, q[j].w, s1);
            } else {
                s0 = fmaf(x[j].x, q[j].x, s0);
                s0 = fmaf(x[j].y, q[j].y, s0);
                s0 = fmaf(x[j].z, q[j].z, s0);
                s0 = fmaf(x[j].w, q[j].w, s0);
            }
        }
        float s = s0 + s1;
        // reduce across the 16-lane dd-group
        s += __shfl_xor(s, 1);
        s += __shfl_xor(s, 2);
        s += __shfl_xor(s, 4);
        s += __shfl_xor(s, 8);

        float pr;
        if (s > m2 + THR2) {             // rare rescale (defer-max)
            const float scl = exp2f(m2 - s);
            m2 = s; l *= scl;
            #pragma unroll
            for (int j = 0; j < 8; ++j) {
                acc[j].x *= scl; acc[j].y *= scl;
                acc[j].z *= scl; acc[j].w *= scl;
            }
            pr = 1.f;
        } else {
            pr = exp2f(s - m2);          // bounded by 2^THR2
        }
        l += pr;
        #pragma unroll
        for (int j = 0; j < 8; ++j) {
            acc[j].x = fmaf(pr, x[j].x, acc[j].x);
            acc[j].y = fmaf(pr, x[j].y, acc[j].y);
            acc[j].z = fmaf(pr, x[j].z, acc[j].z);
            acc[j].w = fmaf(pr, x[j].w, acc[j].w);
        }
    }

    // ---- write partials: lane owns dims {j*64+dd*4..+3} of its head ----
    float* op = ws_o + (((size_t)b * nchunk + c) * NH + head) * DV + dd * 4;
    #pragma unroll
    for (int j = 0; j < 8; ++j)
        *(float4*)(op + j * 64) = acc[j];
    if (dd == 0) {
        const size_t mlb = (((size_t)b * nchunk + c) * NH + head) * 2;
        ws_ml[mlb]     = m2;             // log2-domain running max
        ws_ml[mlb + 1] = l;
    }
}

__global__ __launch_bounds__(256)
void mla_reduce(const int* __restrict__ lens,
                const float* __restrict__ ws_o,
                const float* __restrict__ ws_ml,
                float* __restrict__ out,
                int nchunk, int chunk)
{
    const int h = blockIdx.x;
    const int b = blockIdx.y;
    const int tid = (int)threadIdx.x;
    const int total = lens[b] + 1;
    const int nact = min(nchunk, (total + chunk - 1) / chunk);

    float M = NEGINF;
    for (int c = 0; c < nact; ++c)
        M = fmaxf(M, ws_ml[(((size_t)b * nchunk + c) * NH + h) * 2]);

    float a0 = 0.f, a1 = 0.f, L = 0.f;
    for (int c = 0; c < nact; ++c) {
        const size_t mlb = (((size_t)b * nchunk + c) * NH + h) * 2;
        const float w = exp2f(ws_ml[mlb] - M);   // log2-domain merge
        L += w * ws_ml[mlb + 1];
        const float2 o = *(const float2*)&ws_o[
            (((size_t)b * nchunk + c) * NH + h) * (size_t)DV + 2 * tid];
        a0 = fmaf(w, o.x, a0);
        a1 = fmaf(w, o.y, a1);
    }
    const float inv = 1.f / L;
    *(float2*)&out[((size_t)b * NH + h) * (size_t)DV + 2 * tid] =
        make_float2(a0 * inv, a1 * inv);
}

extern "C" void kernel_launch(void* const* d_in, const int* in_sizes, int n_in,
                              void* d_out, int out_size, void* d_ws, size_t ws_size,
                              hipStream_t stream)
{
    (void)in_sizes; (void)n_in; (void)out_size;
    const float* qg    = (const float*)d_in[0];   // [B,H,576]
    const float* kvnew = (const float*)d_in[1];   // [B,1,576]
    const float* cache = (const float*)d_in[2];   // [B,4096,576]
    const int*   lens  = (const int*)d_in[3];     // [B]
    float* out = (float*)d_out;                   // [B,H,512] fp32

    // largest chunk split that fits the workspace (67 MB at nchunk=32;
    // observed ws ~2.4 GB, so nchunk stays 32)
    int nchunk = 32;
    while (nchunk > 1 &&
           (size_t)NB * nchunk * NH * (DV + 2) * sizeof(float) > ws_size)
        nchunk >>= 1;
    const int chunk = MAXLEN / nchunk;

    float* ws_o  = (float*)d_ws;
    float* ws_ml = ws_o + (size_t)NB * nchunk * NH * DV;

    const int nblocks = NB * nchunk * 4;     // one wave per (b, c, headgroup)
    mla_wave<<<nblocks, 64, 0, stream>>>(qg, kvnew, cache, lens, ws_o, ws_ml,
                                         nchunk, chunk);
    dim3 gB(NH, NB);
    mla_reduce<<<gB, 256, 0, stream>>>(lens, ws_o, ws_ml, out, nchunk, chunk);
}

// Round 8
// 182.671 us; speedup vs baseline: 1.9377x; 1.9377x over previous
//
#include <hip/hip_runtime.h>
#include <math.h>

// MLA decode attention, flash-decoding split + bf16 MFMA core.
// B=64, H=16, latent D=576, V=512, MAX_LEN=4096. fp32 in/out.
//
// R7: matrix-core rewrite (R2..R6 showed the fp32 VALU path is capped ~224us
// by per-row issue cost; every VGPR-costing VALU restructure regressed).
//  - Block = 256 thr (4 waves) per (batch, chunk). Round = 32 rows.
//  - Stage: K rows 0..31 -> LDS bf16 row-major K_s[32][584] (pad: 16B-aligned
//    rows, 2-way banks). V -> LDS bf16 TRANSPOSED Vt[512][36] (MFMA B-frags
//    are k(=row)-contiguous per lane; transpose is unavoidable, done once
//    per round, amortized over all 16 heads).
//  - Scores: S[16h,32r] = Q·K^T as 2x18 mfma_f32_16x16x32_bf16; Q A-frags
//    preloaded (18 frags, 72 VGPR), scale*log2e folded into Q. All 4 waves
//    compute scores redundantly (no cross-wave softmax traffic/barriers).
//  - k-dim safety: A and B frags both loaded with k = kc*32+8*(l>>4)+j; the
//    MFMA dot is invariant under any consistent k-permutation, so the exact
//    HW k-mapping doesn't matter. D-layout (col=lane&15, row=4*(lane>>4)+reg)
//    is the m89-verified one.
//  - Softmax: lane owns 4 head-channels x 1 row; shfl_xor(1,2,4,8) reduce;
//    always-rescale online update (branch-free), log2 domain.
//  - P: cvt to bf16, per-wave private LDS transpose (P_s[16][40]), re-read as
//    the PV A-frag; PV: 8 mfma per wave over its private 128 v-columns.
//  - LDS 79360 B -> exactly 2 blocks/CU; second block covers stage latency.

typedef __attribute__((ext_vector_type(8))) short bf16x8;
typedef __attribute__((ext_vector_type(4))) float f32x4;

namespace {
constexpr int NB = 64, NH = 16, MAXLEN = 4096, D = 576, DV = 512;
constexpr int KP = 584;   // K_s row stride (bf16): 1168 B rows, 16B-aligned
constexpr int VP = 36;    // Vt row stride (bf16): 72 B rows, 8B-aligned
constexpr int PP = 40;    // P_s row stride (bf16): 80 B rows, 16B-aligned
constexpr float SCALE_LOG2E = 0.041666666666666664f * 1.4426950408889634f;
constexpr float NEGINF = -1e30f;
}

__device__ __forceinline__ uint32_t cvtpk(float a, float b) {
    uint32_t r;
    asm("v_cvt_pk_bf16_f32 %0, %1, %2" : "=v"(r) : "v"(a), "v"(b));
    return r;   // low16 = bf16(a), high16 = bf16(b)
}

union FragAB { bf16x8 v; uint32_t u[4]; };

__global__ __launch_bounds__(256, 2)
void mla_mfma(const float* __restrict__ qg, const float* __restrict__ kvnew,
              const float* __restrict__ cache, const int* __restrict__ lens,
              float* __restrict__ ws_o, float* __restrict__ ws_ml,
              int nchunk, int chunk)
{
    const int c = blockIdx.x, b = blockIdx.y;
    const int total = lens[b] + 1;
    const int start = c * chunk;
    if (start >= total) return;               // uniform, before any barrier
    const int end = min(start + chunk, total);
    const int newpos = total - 1;

    __shared__ short K_s[32 * KP];            // 37376 B
    __shared__ short V_s[DV * VP];            // 36864 B
    __shared__ short P_s[4 * 16 * PP];        //  5120 B   (total 79360)

    const int tid  = (int)threadIdx.x;
    const int wave = tid >> 6, lane = tid & 63;
    const int lr = lane & 15, g = lane >> 4;

    const float* vnew = kvnew + (size_t)b * D;
    const float* cb   = cache + (size_t)b * MAXLEN * D;

    // ---- Q A-frags: lane holds Q[h=lr][kc*32 + g*8 + j], scale folded ----
    FragAB qf[18];
    {
        const float* qrow = qg + ((size_t)b * NH + lr) * D + g * 8;
        #pragma unroll
        for (int kc = 0; kc < 18; ++kc) {
            float4 x = *(const float4*)(qrow + kc * 32);
            float4 y = *(const float4*)(qrow + kc * 32 + 4);
            qf[kc].u[0] = cvtpk(x.x * SCALE_LOG2E, x.y * SCALE_LOG2E);
            qf[kc].u[1] = cvtpk(x.z * SCALE_LOG2E, x.w * SCALE_LOG2E);
            qf[kc].u[2] = cvtpk(y.x * SCALE_LOG2E, y.y * SCALE_LOG2E);
            qf[kc].u[3] = cvtpk(y.z * SCALE_LOG2E, y.w * SCALE_LOG2E);
        }
    }

    f32x4 acc[8];
    #pragma unroll
    for (int i = 0; i < 8; ++i) acc[i] = (f32x4){0.f, 0.f, 0.f, 0.f};
    float m2[4] = {NEGINF, NEGINF, NEGINF, NEGINF};
    float ll[4] = {0.f, 0.f, 0.f, 0.f};

    const int krow = tid >> 3;                // staging: 8 threads per row
    const int kf4  = tid & 7;

    for (int r0 = start; r0 < end; r0 += 32) {
        __syncthreads();                      // prev round's LDS reads done

        // ---- stage K: 32 rows fp32 -> bf16 row-major (rows always <4096) --
        {
            const int grow = r0 + krow;
            const float* src = (grow == newpos) ? vnew
                                                : (cb + (size_t)grow * D);
            short* dst = &K_s[krow * KP];
            for (int it = 0; it < 18; ++it) {
                const int f4 = kf4 + 8 * it;
                float4 x = *(const float4*)(src + f4 * 4);
                uint2 w;
                w.x = cvtpk(x.x, x.y);
                w.y = cvtpk(x.z, x.w);
                *(uint2*)&dst[f4 * 4] = w;
            }
        }
        // ---- stage Vt: V[r][v] -> Vt[v][r] bf16 (coalesced col gathers) ---
        for (int vv = 0; vv < 2; ++vv) {
            const int v = tid + 256 * vv;
            for (int rb = 0; rb < 4; ++rb) {
                float f[8];
                #pragma unroll
                for (int j = 0; j < 8; ++j) {
                    const int grow = r0 + rb * 8 + j;
                    const float* src = (grow == newpos)
                        ? (vnew + v) : (cb + (size_t)grow * D + v);
                    f[j] = *src;
                }
                uint2 w0, w1;
                w0.x = cvtpk(f[0], f[1]); w0.y = cvtpk(f[2], f[3]);
                w1.x = cvtpk(f[4], f[5]); w1.y = cvtpk(f[6], f[7]);
                *(uint2*)&V_s[v * VP + rb * 8]     = w0;
                *(uint2*)&V_s[v * VP + rb * 8 + 4] = w1;
            }
        }
        __syncthreads();                      // stage visible to all waves

        // ---- scores: S[16h, 32r], two 16x16 tiles ----
        f32x4 sc0 = (f32x4){0.f, 0.f, 0.f, 0.f};
        f32x4 sc1 = (f32x4){0.f, 0.f, 0.f, 0.f};
        #pragma unroll
        for (int kc = 0; kc < 18; ++kc) {
            FragAB kb0, kb1;
            kb0.v = *(const bf16x8*)&K_s[lr * KP + kc * 32 + g * 8];
            kb1.v = *(const bf16x8*)&K_s[(16 + lr) * KP + kc * 32 + g * 8];
            sc0 = __builtin_amdgcn_mfma_f32_16x16x32_bf16(qf[kc].v, kb0.v, sc0, 0, 0, 0);
            sc1 = __builtin_amdgcn_mfma_f32_16x16x32_bf16(qf[kc].v, kb1.v, sc1, 0, 0, 0);
        }
        // mask invalid rows (lane's D-col = row r0+lr / r0+16+lr)
        if (r0 + lr >= end)      sc0 = (f32x4){NEGINF, NEGINF, NEGINF, NEGINF};
        if (r0 + 16 + lr >= end) sc1 = (f32x4){NEGINF, NEGINF, NEGINF, NEGINF};

        // ---- online softmax, 4 head-channels per lane (log2 domain) ----
        float p0[4], p1[4], scl[4];
        #pragma unroll
        for (int i = 0; i < 4; ++i) {
            float mt = fmaxf(sc0[i], sc1[i]);
            mt = fmaxf(mt, __shfl_xor(mt, 1));
            mt = fmaxf(mt, __shfl_xor(mt, 2));
            mt = fmaxf(mt, __shfl_xor(mt, 4));
            mt = fmaxf(mt, __shfl_xor(mt, 8));
            const float nm = fmaxf(m2[i], mt);
            scl[i] = exp2f(m2[i] - nm);
            p0[i] = exp2f(sc0[i] - nm);
            p1[i] = exp2f(sc1[i] - nm);
            float rs = p0[i] + p1[i];
            rs += __shfl_xor(rs, 1);
            rs += __shfl_xor(rs, 2);
            rs += __shfl_xor(rs, 4);
            rs += __shfl_xor(rs, 8);
            ll[i] = ll[i] * scl[i] + rs;
            m2[i] = nm;
        }

        // ---- P -> bf16, per-wave LDS transpose, re-read as PV A-frag ----
        short* pw = &P_s[wave * 16 * PP];
        #pragma unroll
        for (int i = 0; i < 4; ++i) {
            pw[(4 * g + i) * PP + lr]      = (short)cvtpk(p0[i], p0[i]);
            pw[(4 * g + i) * PP + 16 + lr] = (short)cvtpk(p1[i], p1[i]);
        }
        asm volatile("s_waitcnt lgkmcnt(0)" ::: "memory");  // intra-wave RAW
        FragAB pa;
        pa.v = *(const bf16x8*)&pw[lr * PP + g * 8];

        // ---- PV: wave's 128 v-cols, 8 mfma; rescale acc per head-channel --
        const f32x4 scl4 = (f32x4){scl[0], scl[1], scl[2], scl[3]};
        #pragma unroll
        for (int vt = 0; vt < 8; ++vt) {
            const int v = wave * 128 + vt * 16 + lr;
            FragAB vb;
            *(uint2*)&vb.u[0] = *(const uint2*)&V_s[v * VP + g * 8];
            *(uint2*)&vb.u[2] = *(const uint2*)&V_s[v * VP + g * 8 + 4];
            acc[vt] = acc[vt] * scl4;
            acc[vt] = __builtin_amdgcn_mfma_f32_16x16x32_bf16(pa.v, vb.v, acc[vt], 0, 0, 0);
        }
    }

    // ---- write partials: lane covers h = 4g+i, v = wave*128 + vt*16 + lr --
    float* ob = ws_o + (((size_t)b * nchunk + c) * NH) * DV;
    #pragma unroll
    for (int vt = 0; vt < 8; ++vt) {
        const int v = wave * 128 + vt * 16 + lr;
        #pragma unroll
        for (int i = 0; i < 4; ++i)
            ob[(4 * g + i) * DV + v] = acc[vt][i];
    }
    if (wave == 0 && lr == 0) {
        float* mlb = ws_ml + ((size_t)b * nchunk + c) * NH * 2;
        #pragma unroll
        for (int i = 0; i < 4; ++i) {
            mlb[(4 * g + i) * 2]     = m2[i];   // log2-domain running max
            mlb[(4 * g + i) * 2 + 1] = ll[i];
        }
    }
}

__global__ __launch_bounds__(256)
void mla_reduce(const int* __restrict__ lens,
                const float* __restrict__ ws_o,
                const float* __restrict__ ws_ml,
                float* __restrict__ out,
                int nchunk, int chunk)
{
    const int h = blockIdx.x;
    const int b = blockIdx.y;
    const int tid = (int)threadIdx.x;
    const int total = lens[b] + 1;
    const int nact = min(nchunk, (total + chunk - 1) / chunk);

    float M = NEGINF;
    for (int c = 0; c < nact; ++c)
        M = fmaxf(M, ws_ml[(((size_t)b * nchunk + c) * NH + h) * 2]);

    float a0 = 0.f, a1 = 0.f, L = 0.f;
    for (int c = 0; c < nact; ++c) {
        const size_t mlb = (((size_t)b * nchunk + c) * NH + h) * 2;
        const float w = exp2f(ws_ml[mlb] - M);   // log2-domain merge
        L += w * ws_ml[mlb + 1];
        const float2 o = *(const float2*)&ws_o[
            (((size_t)b * nchunk + c) * NH + h) * (size_t)DV + 2 * tid];
        a0 = fmaf(w, o.x, a0);
        a1 = fmaf(w, o.y, a1);
    }
    const float inv = 1.f / L;
    *(float2*)&out[((size_t)b * NH + h) * (size_t)DV + 2 * tid] =
        make_float2(a0 * inv, a1 * inv);
}

extern "C" void kernel_launch(void* const* d_in, const int* in_sizes, int n_in,
                              void* d_out, int out_size, void* d_ws, size_t ws_size,
                              hipStream_t stream)
{
    (void)in_sizes; (void)n_in; (void)out_size;
    const float* qg    = (const float*)d_in[0];   // [B,H,576]
    const float* kvnew = (const float*)d_in[1];   // [B,1,576]
    const float* cache = (const float*)d_in[2];   // [B,4096,576]
    const int*   lens  = (const int*)d_in[3];     // [B]
    float* out = (float*)d_out;                   // [B,H,512] fp32

    // largest chunk split that fits the workspace (67 MB at nchunk=32)
    int nchunk = 32;
    while (nchunk > 1 &&
           (size_t)NB * nchunk * NH * (DV + 2) * sizeof(float) > ws_size)
        nchunk >>= 1;
    const int chunk = MAXLEN / nchunk;            // multiple of 32

    float* ws_o  = (float*)d_ws;
    float* ws_ml = ws_o + (size_t)NB * nchunk * NH * DV;

    dim3 gA(nchunk, NB);
    mla_mfma<<<gA, 256, 0, stream>>>(qg, kvnew, cache, lens, ws_o, ws_ml,
                                     nchunk, chunk);
    dim3 gB(NH, NB);
    mla_reduce<<<gB, 256, 0, stream>>>(lens, ws_o, ws_ml, out, nchunk, chunk);
}

// Round 10
// 158.817 us; speedup vs baseline: 2.2288x; 1.1502x over previous
//
#include <hip/hip_runtime.h>
#include <math.h>

// MLA decode attention, flash-decoding split + bf16 MFMA core.
// B=64, H=16, latent D=576, V=512, MAX_LEN=4096. fp32 in/out.
//
// R9 = R7 (182us, correct) with the V-staging global re-read removed.
//  - R8's ds_read_b64_tr_b16 path hit its pre-declared failure signature
//    (absmax 1.2 ~ layout wrong) -> reverted to R7's verified Vt[v][r] +
//    plain b64 B-frag reads, canonical k=8g+j on both MFMA operands.
//  - Staging re-tiled: each thread loads a 4row x 4col fp32 block (18
//    coalesced float4 loads/thread/round as before), then dual-writes:
//    row-wise to K_s[32][584] (4x ds_write_b64) and LOCALLY TRANSPOSED
//    column-wise to Vt[512][36] (4x ds_write_b64). V-transpose now costs
//    16 LDS writes + 32 cvtpk per thread instead of 64 serialized L2-hit
//    scalar global loads -- R7's dominant modeled cost.
//  - Unchanged from R7: 4 waves redundant 16hx32r scores (Q A-frags
//    preloaded, scale folded, log2 domain), shfl softmax, P_s per-wave
//    transpose, PV 8 mfma/wave over private 128 v-cols, LDS 79360 B
//    (2 blocks/CU), flash-decoding reduce kernel.

typedef __attribute__((ext_vector_type(8))) short bf16x8;
typedef __attribute__((ext_vector_type(4))) float f32x4;

namespace {
constexpr int NB = 64, NH = 16, MAXLEN = 4096, D = 576, DV = 512;
constexpr int KP = 584;   // K_s row stride (bf16): 1168 B rows, 16B-aligned
constexpr int VP = 36;    // Vt row stride (bf16): 72 B rows, 8B-aligned
constexpr int PP = 40;    // P_s row stride (bf16)
constexpr float SCALE_LOG2E = 0.041666666666666664f * 1.4426950408889634f;
constexpr float NEGINF = -1e30f;
}

__device__ __forceinline__ uint32_t cvtpk(float a, float b) {
    uint32_t r;
    asm("v_cvt_pk_bf16_f32 %0, %1, %2" : "=v"(r) : "v"(a), "v"(b));
    return r;   // low16 = bf16(a), high16 = bf16(b)
}

union FragAB { bf16x8 v; uint32_t u[4]; };

__global__ __launch_bounds__(256, 2)
void mla_mfma(const float* __restrict__ qg, const float* __restrict__ kvnew,
              const float* __restrict__ cache, const int* __restrict__ lens,
              float* __restrict__ ws_o, float* __restrict__ ws_ml,
              int nchunk, int chunk)
{
    const int c = blockIdx.x, b = blockIdx.y;
    const int total = lens[b] + 1;
    const int start = c * chunk;
    if (start >= total) return;               // uniform, before any barrier
    const int end = min(start + chunk, total);
    const int newpos = total - 1;

    __shared__ short K_s[32 * KP];            // 37376 B row-major bf16
    __shared__ short V_s[DV * VP];            // 36864 B Vt[v][r] bf16
    __shared__ short P_s[4 * 16 * PP];        //  5120 B   (total 79360)

    const int tid  = (int)threadIdx.x;
    const int wave = tid >> 6, lane = tid & 63;
    const int lr = lane & 15, g = lane >> 4;

    const float* vnew = kvnew + (size_t)b * D;
    const float* cb   = cache + (size_t)b * MAXLEN * D;

    // ---- Q A-frags: lane holds Q[h=lr][kc*32 + g*8 + j], scale folded ----
    FragAB qf[18];
    {
        const float* qrow = qg + ((size_t)b * NH + lr) * D + g * 8;
        #pragma unroll
        for (int kc = 0; kc < 18; ++kc) {
            float4 x = *(const float4*)(qrow + kc * 32);
            float4 y = *(const float4*)(qrow + kc * 32 + 4);
            qf[kc].u[0] = cvtpk(x.x * SCALE_LOG2E, x.y * SCALE_LOG2E);
            qf[kc].u[1] = cvtpk(x.z * SCALE_LOG2E, x.w * SCALE_LOG2E);
            qf[kc].u[2] = cvtpk(y.x * SCALE_LOG2E, y.y * SCALE_LOG2E);
            qf[kc].u[3] = cvtpk(y.z * SCALE_LOG2E, y.w * SCALE_LOG2E);
        }
    }

    f32x4 acc[8];
    #pragma unroll
    for (int i = 0; i < 8; ++i) acc[i] = (f32x4){0.f, 0.f, 0.f, 0.f};
    float m2[4] = {NEGINF, NEGINF, NEGINF, NEGINF};
    float ll[4] = {0.f, 0.f, 0.f, 0.f};

    const int rg = tid >> 5;                  // staging row-group: rows rg*4+i
    const int cl = tid & 31;                  // staging col-lane

    for (int r0 = start; r0 < end; r0 += 32) {
        __syncthreads();                      // prev round's LDS reads done

        // ---- stage: 4x4 fp32 blocks -> bf16, dual-write K_s + Vt ----
        #pragma unroll
        for (int it = 0; it < 5; ++it) {
            const int cf = 32 * it + cl;      // float4-column 0..143
            if (cf < 144) {
                float4 m0, m1, m2_, m3;
                {
                    const int gr0 = r0 + rg * 4;
                    const float* s0 = (gr0     == newpos) ? vnew : (cb + (size_t)(gr0    ) * D);
                    const float* s1 = (gr0 + 1 == newpos) ? vnew : (cb + (size_t)(gr0 + 1) * D);
                    const float* s2 = (gr0 + 2 == newpos) ? vnew : (cb + (size_t)(gr0 + 2) * D);
                    const float* s3 = (gr0 + 3 == newpos) ? vnew : (cb + (size_t)(gr0 + 3) * D);
                    m0 = *(const float4*)(s0 + cf * 4);
                    m1 = *(const float4*)(s1 + cf * 4);
                    m2_ = *(const float4*)(s2 + cf * 4);
                    m3 = *(const float4*)(s3 + cf * 4);
                }
                uint2 w;
                // K_s row-major writes (4 rows x 4 cols)
                w.x = cvtpk(m0.x, m0.y); w.y = cvtpk(m0.z, m0.w);
                *(uint2*)&K_s[(rg * 4 + 0) * KP + cf * 4] = w;
                w.x = cvtpk(m1.x, m1.y); w.y = cvtpk(m1.z, m1.w);
                *(uint2*)&K_s[(rg * 4 + 1) * KP + cf * 4] = w;
                w.x = cvtpk(m2_.x, m2_.y); w.y = cvtpk(m2_.z, m2_.w);
                *(uint2*)&K_s[(rg * 4 + 2) * KP + cf * 4] = w;
                w.x = cvtpk(m3.x, m3.y); w.y = cvtpk(m3.z, m3.w);
                *(uint2*)&K_s[(rg * 4 + 3) * KP + cf * 4] = w;
                // Vt transposed writes (V range only: cols < 512)
                if (cf < 128) {
                    const int v0 = cf * 4;
                    w.x = cvtpk(m0.x, m1.x); w.y = cvtpk(m2_.x, m3.x);
                    *(uint2*)&V_s[(v0 + 0) * VP + rg * 4] = w;
                    w.x = cvtpk(m0.y, m1.y); w.y = cvtpk(m2_.y, m3.y);
                    *(uint2*)&V_s[(v0 + 1) * VP + rg * 4] = w;
                    w.x = cvtpk(m0.z, m1.z); w.y = cvtpk(m2_.z, m3.z);
                    *(uint2*)&V_s[(v0 + 2) * VP + rg * 4] = w;
                    w.x = cvtpk(m0.w, m1.w); w.y = cvtpk(m2_.w, m3.w);
                    *(uint2*)&V_s[(v0 + 3) * VP + rg * 4] = w;
                }
            }
        }
        __syncthreads();                      // stage visible to all waves

        // ---- scores: S[16h, 32r], two 16x16 tiles ----
        f32x4 sc0 = (f32x4){0.f, 0.f, 0.f, 0.f};
        f32x4 sc1 = (f32x4){0.f, 0.f, 0.f, 0.f};
        #pragma unroll
        for (int kc = 0; kc < 18; ++kc) {
            FragAB kb0, kb1;
            kb0.v = *(const bf16x8*)&K_s[lr * KP + kc * 32 + g * 8];
            kb1.v = *(const bf16x8*)&K_s[(16 + lr) * KP + kc * 32 + g * 8];
            sc0 = __builtin_amdgcn_mfma_f32_16x16x32_bf16(qf[kc].v, kb0.v, sc0, 0, 0, 0);
            sc1 = __builtin_amdgcn_mfma_f32_16x16x32_bf16(qf[kc].v, kb1.v, sc1, 0, 0, 0);
        }
        // mask invalid rows (lane's D-col = row r0+lr / r0+16+lr)
        if (r0 + lr >= end)      sc0 = (f32x4){NEGINF, NEGINF, NEGINF, NEGINF};
        if (r0 + 16 + lr >= end) sc1 = (f32x4){NEGINF, NEGINF, NEGINF, NEGINF};

        // ---- online softmax, 4 head-channels per lane (log2 domain) ----
        float p0[4], p1[4], scl[4];
        #pragma unroll
        for (int i = 0; i < 4; ++i) {
            float mt = fmaxf(sc0[i], sc1[i]);
            mt = fmaxf(mt, __shfl_xor(mt, 1));
            mt = fmaxf(mt, __shfl_xor(mt, 2));
            mt = fmaxf(mt, __shfl_xor(mt, 4));
            mt = fmaxf(mt, __shfl_xor(mt, 8));
            const float nm = fmaxf(m2[i], mt);
            scl[i] = exp2f(m2[i] - nm);
            p0[i] = exp2f(sc0[i] - nm);
            p1[i] = exp2f(sc1[i] - nm);
            float rs = p0[i] + p1[i];
            rs += __shfl_xor(rs, 1);
            rs += __shfl_xor(rs, 2);
            rs += __shfl_xor(rs, 4);
            rs += __shfl_xor(rs, 8);
            ll[i] = ll[i] * scl[i] + rs;
            m2[i] = nm;
        }

        // ---- P -> bf16, per-wave LDS transpose, re-read as PV A-frag ----
        short* pw = &P_s[wave * 16 * PP];
        #pragma unroll
        for (int i = 0; i < 4; ++i) {
            pw[(4 * g + i) * PP + lr]      = (short)cvtpk(p0[i], p0[i]);
            pw[(4 * g + i) * PP + 16 + lr] = (short)cvtpk(p1[i], p1[i]);
        }
        asm volatile("s_waitcnt lgkmcnt(0)" ::: "memory");  // cross-lane RAW
        FragAB pa;
        pa.v = *(const bf16x8*)&pw[lr * PP + g * 8];

        // ---- PV: wave's 128 v-cols, 8 mfma; rescale acc per head-chan ----
        const f32x4 scl4 = (f32x4){scl[0], scl[1], scl[2], scl[3]};
        #pragma unroll
        for (int vt = 0; vt < 8; ++vt) {
            const int v = wave * 128 + vt * 16 + lr;
            FragAB vb;
            *(uint2*)&vb.u[0] = *(const uint2*)&V_s[v * VP + g * 8];
            *(uint2*)&vb.u[2] = *(const uint2*)&V_s[v * VP + g * 8 + 4];
            acc[vt] = acc[vt] * scl4;
            acc[vt] = __builtin_amdgcn_mfma_f32_16x16x32_bf16(pa.v, vb.v, acc[vt], 0, 0, 0);
        }
    }

    // ---- write partials: lane covers h = 4g+i, v = wave*128 + vt*16 + lr --
    float* ob = ws_o + (((size_t)b * nchunk + c) * NH) * DV;
    #pragma unroll
    for (int vt = 0; vt < 8; ++vt) {
        const int v = wave * 128 + vt * 16 + lr;
        #pragma unroll
        for (int i = 0; i < 4; ++i)
            ob[(4 * g + i) * DV + v] = acc[vt][i];
    }
    if (wave == 0 && lr == 0) {
        float* mlb = ws_ml + ((size_t)b * nchunk + c) * NH * 2;
        #pragma unroll
        for (int i = 0; i < 4; ++i) {
            mlb[(4 * g + i) * 2]     = m2[i];   // log2-domain running max
            mlb[(4 * g + i) * 2 + 1] = ll[i];
        }
    }
}

__global__ __launch_bounds__(256)
void mla_reduce(const int* __restrict__ lens,
                const float* __restrict__ ws_o,
                const float* __restrict__ ws_ml,
                float* __restrict__ out,
                int nchunk, int chunk)
{
    const int h = blockIdx.x;
    const int b = blockIdx.y;
    const int tid = (int)threadIdx.x;
    const int total = lens[b] + 1;
    const int nact = min(nchunk, (total + chunk - 1) / chunk);

    float M = NEGINF;
    for (int c = 0; c < nact; ++c)
        M = fmaxf(M, ws_ml[(((size_t)b * nchunk + c) * NH + h) * 2]);

    float a0 = 0.f, a1 = 0.f, L = 0.f;
    for (int c = 0; c < nact; ++c) {
        const size_t mlb = (((size_t)b * nchunk + c) * NH + h) * 2;
        const float w = exp2f(ws_ml[mlb] - M);   // log2-domain merge
        L += w * ws_ml[mlb + 1];
        const float2 o = *(const float2*)&ws_o[
            (((size_t)b * nchunk + c) * NH + h) * (size_t)DV + 2 * tid];
        a0 = fmaf(w, o.x, a0);
        a1 = fmaf(w, o.y, a1);
    }
    const float inv = 1.f / L;
    *(float2*)&out[((size_t)b * NH + h) * (size_t)DV + 2 * tid] =
        make_float2(a0 * inv, a1 * inv);
}

extern "C" void kernel_launch(void* const* d_in, const int* in_sizes, int n_in,
                              void* d_out, int out_size, void* d_ws, size_t ws_size,
                              hipStream_t stream)
{
    (void)in_sizes; (void)n_in; (void)out_size;
    const float* qg    = (const float*)d_in[0];   // [B,H,576]
    const float* kvnew = (const float*)d_in[1];   // [B,1,576]
    const float* cache = (const float*)d_in[2];   // [B,4096,576]
    const int*   lens  = (const int*)d_in[3];     // [B]
    float* out = (float*)d_out;                   // [B,H,512] fp32

    // largest chunk split that fits the workspace (67 MB at nchunk=32)
    int nchunk = 32;
    while (nchunk > 1 &&
           (size_t)NB * nchunk * NH * (DV + 2) * sizeof(float) > ws_size)
        nchunk >>= 1;
    const int chunk = MAXLEN / nchunk;            // multiple of 32

    float* ws_o  = (float*)d_ws;
    float* ws_ml = ws_o + (size_t)NB * nchunk * NH * DV;

    dim3 gA(nchunk, NB);
    mla_mfma<<<gA, 256, 0, stream>>>(qg, kvnew, cache, lens, ws_o, ws_ml,
                                     nchunk, chunk);
    dim3 gB(NH, NB);
    mla_reduce<<<gB, 256, 0, stream>>>(lens, ws_o, ws_ml, out, nchunk, chunk);
}

// Round 11
// 145.610 us; speedup vs baseline: 2.4309x; 1.0907x over previous
//
#include <hip/hip_runtime.h>
#include <math.h>

// MLA decode attention, flash-decoding split + bf16 MFMA core.
// B=64, H=16, latent D=576, V=512, MAX_LEN=4096. fp32 in/out.
//
// R10 change vs R9 (158.8us): T14 async-STAGE split (issue-early/write-late).
//  - R9 alternated stage(HBM busy)/compute(HBM idle) with aligned barriers:
//    per-CU bandwidth-latency (~72KB/round ~ 7200cy at per-CU HBM share)
//    half-exposed -> 3x above the 48us HBM floor.
//  - Now: next round's 18 global_load_dwordx4 are ISSUED into registers
//    before the current round's compute; after the post-compute barrier the
//    values are cvtpk'd + ds_written. HBM stays busy under compute. LDS
//    stays single-buffered (79360B, 2 blocks/CU preserved).
//  - Staged regs nx[5][4] float4: fully unrolled static indexing (rule #20);
//    +72 VGPR in flight -> ~230 total, inside launch_bounds(256,2)'s cap.
//  - Row bounds: next-round stage only when r0+32 < end <= 4095, so staged
//    rows <= 4095 -- always inside the 4096-row cache.
//  - Everything else = R9: dual-write K_s row-major + Vt transposed during
//    stage, 4-wave redundant scores, log2 softmax, P_s transpose, PV 8
//    mfma/wave, flash-decoding reduce kernel.

typedef __attribute__((ext_vector_type(8))) short bf16x8;
typedef __attribute__((ext_vector_type(4))) float f32x4;

namespace {
constexpr int NB = 64, NH = 16, MAXLEN = 4096, D = 576, DV = 512;
constexpr int KP = 584;   // K_s row stride (bf16): 1168 B rows, 16B-aligned
constexpr int VP = 36;    // Vt row stride (bf16): 72 B rows, 8B-aligned
constexpr int PP = 40;    // P_s row stride (bf16)
constexpr float SCALE_LOG2E = 0.041666666666666664f * 1.4426950408889634f;
constexpr float NEGINF = -1e30f;
}

__device__ __forceinline__ uint32_t cvtpk(float a, float b) {
    uint32_t r;
    asm("v_cvt_pk_bf16_f32 %0, %1, %2" : "=v"(r) : "v"(a), "v"(b));
    return r;   // low16 = bf16(a), high16 = bf16(b)
}

union FragAB { bf16x8 v; uint32_t u[4]; };

__global__ __launch_bounds__(256, 2)
void mla_mfma(const float* __restrict__ qg, const float* __restrict__ kvnew,
              const float* __restrict__ cache, const int* __restrict__ lens,
              float* __restrict__ ws_o, float* __restrict__ ws_ml,
              int nchunk, int chunk)
{
    const int c = blockIdx.x, b = blockIdx.y;
    const int total = lens[b] + 1;
    const int start = c * chunk;
    if (start >= total) return;               // uniform, before any barrier
    const int end = min(start + chunk, total);
    const int newpos = total - 1;

    __shared__ short K_s[32 * KP];            // 37376 B row-major bf16
    __shared__ short V_s[DV * VP];            // 36864 B Vt[v][r] bf16
    __shared__ short P_s[4 * 16 * PP];        //  5120 B   (total 79360)

    const int tid  = (int)threadIdx.x;
    const int wave = tid >> 6, lane = tid & 63;
    const int lr = lane & 15, g = lane >> 4;

    const float* vnew = kvnew + (size_t)b * D;
    const float* cb   = cache + (size_t)b * MAXLEN * D;

    const int rg = tid >> 5;                  // staging row-group: rows rg*4+i
    const int cl = tid & 31;                  // staging col-lane

    float4 nx[5][4];                          // in-flight stage registers

    // STAGE_LOAD: issue next tile's global loads into nx (no waits here)
#define STAGE_LOAD(R0N)                                                        \
    {                                                                          \
        const int gr0 = (R0N) + rg * 4;                                        \
        const float* s0 = (gr0     == newpos) ? vnew : (cb + (size_t)(gr0    ) * D); \
        const float* s1 = (gr0 + 1 == newpos) ? vnew : (cb + (size_t)(gr0 + 1) * D); \
        const float* s2 = (gr0 + 2 == newpos) ? vnew : (cb + (size_t)(gr0 + 2) * D); \
        const float* s3 = (gr0 + 3 == newpos) ? vnew : (cb + (size_t)(gr0 + 3) * D); \
        _Pragma("unroll")                                                      \
        for (int it = 0; it < 5; ++it) {                                       \
            const int cf = 32 * it + cl;                                       \
            if (cf < 144) {                                                    \
                nx[it][0] = *(const float4*)(s0 + cf * 4);                     \
                nx[it][1] = *(const float4*)(s1 + cf * 4);                     \
                nx[it][2] = *(const float4*)(s2 + cf * 4);                     \
                nx[it][3] = *(const float4*)(s3 + cf * 4);                     \
            }                                                                  \
        }                                                                      \
    }

    // STAGE_WRITE: cvtpk nx -> K_s (row-major) + Vt (transposed)
#define STAGE_WRITE()                                                          \
    {                                                                          \
        _Pragma("unroll")                                                      \
        for (int it = 0; it < 5; ++it) {                                       \
            const int cf = 32 * it + cl;                                       \
            if (cf < 144) {                                                    \
                uint2 w;                                                       \
                w.x = cvtpk(nx[it][0].x, nx[it][0].y);                         \
                w.y = cvtpk(nx[it][0].z, nx[it][0].w);                         \
                *(uint2*)&K_s[(rg * 4 + 0) * KP + cf * 4] = w;                 \
                w.x = cvtpk(nx[it][1].x, nx[it][1].y);                         \
                w.y = cvtpk(nx[it][1].z, nx[it][1].w);                         \
                *(uint2*)&K_s[(rg * 4 + 1) * KP + cf * 4] = w;                 \
                w.x = cvtpk(nx[it][2].x, nx[it][2].y);                         \
                w.y = cvtpk(nx[it][2].z, nx[it][2].w);                         \
                *(uint2*)&K_s[(rg * 4 + 2) * KP + cf * 4] = w;                 \
                w.x = cvtpk(nx[it][3].x, nx[it][3].y);                         \
                w.y = cvtpk(nx[it][3].z, nx[it][3].w);                         \
                *(uint2*)&K_s[(rg * 4 + 3) * KP + cf * 4] = w;                 \
                if (cf < 128) {                                                \
                    const int v0 = cf * 4;                                     \
                    w.x = cvtpk(nx[it][0].x, nx[it][1].x);                     \
                    w.y = cvtpk(nx[it][2].x, nx[it][3].x);                     \
                    *(uint2*)&V_s[(v0 + 0) * VP + rg * 4] = w;                 \
                    w.x = cvtpk(nx[it][0].y, nx[it][1].y);                     \
                    w.y = cvtpk(nx[it][2].y, nx[it][3].y);                     \
                    *(uint2*)&V_s[(v0 + 1) * VP + rg * 4] = w;                 \
                    w.x = cvtpk(nx[it][0].z, nx[it][1].z);                     \
                    w.y = cvtpk(nx[it][2].z, nx[it][3].z);                     \
                    *(uint2*)&V_s[(v0 + 2) * VP + rg * 4] = w;                 \
                    w.x = cvtpk(nx[it][0].w, nx[it][1].w);                     \
                    w.y = cvtpk(nx[it][2].w, nx[it][3].w);                     \
                    *(uint2*)&V_s[(v0 + 3) * VP + rg * 4] = w;                 \
                }                                                              \
            }                                                                  \
        }                                                                      \
    }

    // ---- Q A-frags: lane holds Q[h=lr][kc*32 + g*8 + j], scale folded ----
    FragAB qf[18];
    {
        const float* qrow = qg + ((size_t)b * NH + lr) * D + g * 8;
        #pragma unroll
        for (int kc = 0; kc < 18; ++kc) {
            float4 x = *(const float4*)(qrow + kc * 32);
            float4 y = *(const float4*)(qrow + kc * 32 + 4);
            qf[kc].u[0] = cvtpk(x.x * SCALE_LOG2E, x.y * SCALE_LOG2E);
            qf[kc].u[1] = cvtpk(x.z * SCALE_LOG2E, x.w * SCALE_LOG2E);
            qf[kc].u[2] = cvtpk(y.x * SCALE_LOG2E, y.y * SCALE_LOG2E);
            qf[kc].u[3] = cvtpk(y.z * SCALE_LOG2E, y.w * SCALE_LOG2E);
        }
    }

    f32x4 acc[8];
    #pragma unroll
    for (int i = 0; i < 8; ++i) acc[i] = (f32x4){0.f, 0.f, 0.f, 0.f};
    float m2[4] = {NEGINF, NEGINF, NEGINF, NEGINF};
    float ll[4] = {0.f, 0.f, 0.f, 0.f};

    // ---- prologue: stage tile 0 (load -> write -> barrier) ----
    STAGE_LOAD(start);
    STAGE_WRITE();
    __syncthreads();

    for (int r0 = start; r0 < end; r0 += 32) {
        const bool have_next = (r0 + 32 < end);     // block-uniform
        if (have_next) STAGE_LOAD(r0 + 32);         // issue only; no waits

        // ---- scores: S[16h, 32r], two 16x16 tiles ----
        f32x4 sc0 = (f32x4){0.f, 0.f, 0.f, 0.f};
        f32x4 sc1 = (f32x4){0.f, 0.f, 0.f, 0.f};
        #pragma unroll
        for (int kc = 0; kc < 18; ++kc) {
            FragAB kb0, kb1;
            kb0.v = *(const bf16x8*)&K_s[lr * KP + kc * 32 + g * 8];
            kb1.v = *(const bf16x8*)&K_s[(16 + lr) * KP + kc * 32 + g * 8];
            sc0 = __builtin_amdgcn_mfma_f32_16x16x32_bf16(qf[kc].v, kb0.v, sc0, 0, 0, 0);
            sc1 = __builtin_amdgcn_mfma_f32_16x16x32_bf16(qf[kc].v, kb1.v, sc1, 0, 0, 0);
        }
        // mask invalid rows (lane's D-col = row r0+lr / r0+16+lr)
        if (r0 + lr >= end)      sc0 = (f32x4){NEGINF, NEGINF, NEGINF, NEGINF};
        if (r0 + 16 + lr >= end) sc1 = (f32x4){NEGINF, NEGINF, NEGINF, NEGINF};

        // ---- online softmax, 4 head-channels per lane (log2 domain) ----
        float p0[4], p1[4], scl[4];
        #pragma unroll
        for (int i = 0; i < 4; ++i) {
            float mt = fmaxf(sc0[i], sc1[i]);
            mt = fmaxf(mt, __shfl_xor(mt, 1));
            mt = fmaxf(mt, __shfl_xor(mt, 2));
            mt = fmaxf(mt, __shfl_xor(mt, 4));
            mt = fmaxf(mt, __shfl_xor(mt, 8));
            const float nm = fmaxf(m2[i], mt);
            scl[i] = exp2f(m2[i] - nm);
            p0[i] = exp2f(sc0[i] - nm);
            p1[i] = exp2f(sc1[i] - nm);
            float rs = p0[i] + p1[i];
            rs += __shfl_xor(rs, 1);
            rs += __shfl_xor(rs, 2);
            rs += __shfl_xor(rs, 4);
            rs += __shfl_xor(rs, 8);
            ll[i] = ll[i] * scl[i] + rs;
            m2[i] = nm;
        }

        // ---- P -> bf16, per-wave LDS transpose, re-read as PV A-frag ----
        short* pw = &P_s[wave * 16 * PP];
        #pragma unroll
        for (int i = 0; i < 4; ++i) {
            pw[(4 * g + i) * PP + lr]      = (short)cvtpk(p0[i], p0[i]);
            pw[(4 * g + i) * PP + 16 + lr] = (short)cvtpk(p1[i], p1[i]);
        }
        asm volatile("s_waitcnt lgkmcnt(0)" ::: "memory");  // cross-lane RAW
        FragAB pa;
        pa.v = *(const bf16x8*)&pw[lr * PP + g * 8];

        // ---- PV: wave's 128 v-cols, 8 mfma; rescale acc per head-chan ----
        const f32x4 scl4 = (f32x4){scl[0], scl[1], scl[2], scl[3]};
        #pragma unroll
        for (int vt = 0; vt < 8; ++vt) {
            const int v = wave * 128 + vt * 16 + lr;
            FragAB vb;
            *(uint2*)&vb.u[0] = *(const uint2*)&V_s[v * VP + g * 8];
            *(uint2*)&vb.u[2] = *(const uint2*)&V_s[v * VP + g * 8 + 4];
            acc[vt] = acc[vt] * scl4;
            acc[vt] = __builtin_amdgcn_mfma_f32_16x16x32_bf16(pa.v, vb.v, acc[vt], 0, 0, 0);
        }

        __syncthreads();                      // all waves done reading LDS
        if (have_next) STAGE_WRITE();         // waits on nx loads, writes LDS
        __syncthreads();                      // next round staged
    }

    // ---- write partials: lane covers h = 4g+i, v = wave*128 + vt*16 + lr --
    float* ob = ws_o + (((size_t)b * nchunk + c) * NH) * DV;
    #pragma unroll
    for (int vt = 0; vt < 8; ++vt) {
        const int v = wave * 128 + vt * 16 + lr;
        #pragma unroll
        for (int i = 0; i < 4; ++i)
            ob[(4 * g + i) * DV + v] = acc[vt][i];
    }
    if (wave == 0 && lr == 0) {
        float* mlb = ws_ml + ((size_t)b * nchunk + c) * NH * 2;
        #pragma unroll
        for (int i = 0; i < 4; ++i) {
            mlb[(4 * g + i) * 2]     = m2[i];   // log2-domain running max
            mlb[(4 * g + i) * 2 + 1] = ll[i];
        }
    }
#undef STAGE_LOAD
#undef STAGE_WRITE
}

__global__ __launch_bounds__(256)
void mla_reduce(const int* __restrict__ lens,
                const float* __restrict__ ws_o,
                const float* __restrict__ ws_ml,
                float* __restrict__ out,
                int nchunk, int chunk)
{
    const int h = blockIdx.x;
    const int b = blockIdx.y;
    const int tid = (int)threadIdx.x;
    const int total = lens[b] + 1;
    const int nact = min(nchunk, (total + chunk - 1) / chunk);

    float M = NEGINF;
    for (int c = 0; c < nact; ++c)
        M = fmaxf(M, ws_ml[(((size_t)b * nchunk + c) * NH + h) * 2]);

    float a0 = 0.f, a1 = 0.f, L = 0.f;
    for (int c = 0; c < nact; ++c) {
        const size_t mlb = (((size_t)b * nchunk + c) * NH + h) * 2;
        const float w = exp2f(ws_ml[mlb] - M);   // log2-domain merge
        L += w * ws_ml[mlb + 1];
        const float2 o = *(const float2*)&ws_o[
            (((size_t)b * nchunk + c) * NH + h) * (size_t)DV + 2 * tid];
        a0 = fmaf(w, o.x, a0);
        a1 = fmaf(w, o.y, a1);
    }
    const float inv = 1.f / L;
    *(float2*)&out[((size_t)b * NH + h) * (size_t)DV + 2 * tid] =
        make_float2(a0 * inv, a1 * inv);
}

extern "C" void kernel_launch(void* const* d_in, const int* in_sizes, int n_in,
                              void* d_out, int out_size, void* d_ws, size_t ws_size,
                              hipStream_t stream)
{
    (void)in_sizes; (void)n_in; (void)out_size;
    const float* qg    = (const float*)d_in[0];   // [B,H,576]
    const float* kvnew = (const float*)d_in[1];   // [B,1,576]
    const float* cache = (const float*)d_in[2];   // [B,4096,576]
    const int*   lens  = (const int*)d_in[3];     // [B]
    float* out = (float*)d_out;                   // [B,H,512] fp32

    // largest chunk split that fits the workspace (67 MB at nchunk=32)
    int nchunk = 32;
    while (nchunk > 1 &&
           (size_t)NB * nchunk * NH * (DV + 2) * sizeof(float) > ws_size)
        nchunk >>= 1;
    const int chunk = MAXLEN / nchunk;            // multiple of 32

    float* ws_o  = (float*)d_ws;
    float* ws_ml = ws_o + (size_t)NB * nchunk * NH * DV;

    dim3 gA(nchunk, NB);
    mla_mfma<<<gA, 256, 0, stream>>>(qg, kvnew, cache, lens, ws_o, ws_ml,
                                     nchunk, chunk);
    dim3 gB(NH, NB);
    mla_reduce<<<gB, 256, 0, stream>>>(lens, ws_o, ws_ml, out, nchunk, chunk);
}